// Round 10
// baseline (1422.617 us; speedup 1.0000x reference)
//
#include <hip/hip_runtime.h>
#include <cstddef>

#define BK_SHIFT 8      // 256 nodes per bucket
#define BSTRIDE 8192    // staging slots per bucket (max load ~4400)
#define CHUNK 2048      // edges per workgroup in k_part1 (256 thr x 8)
#define ACHUNK 768      // aggE nodes per block = 3 buckets (48KB+ LDS)
#define OCHUNK 2048     // out2 nodes per block = 8 buckets

typedef unsigned int uint32;
typedef unsigned short ushort;
typedef __attribute__((ext_vector_type(8))) short short8;
typedef __attribute__((ext_vector_type(4))) float f32x4;
typedef __attribute__((ext_vector_type(4))) float float4v;

__device__ __forceinline__ float bf_lo(uint32 v) {
  union { uint32 u; float f; } c; c.u = v << 16; return c.f;
}
__device__ __forceinline__ float bf_hi(uint32 v) {
  union { uint32 u; float f; } c; c.u = v & 0xffff0000u; return c.f;
}
__device__ __forceinline__ uint32 pack_bf2(float a, float b) {  // RNE
  union { float f; uint32 u; } x, y; x.f = a; y.f = b;
  uint32 ua = x.u + 0x7fffu + ((x.u >> 16) & 1u);
  uint32 ub = y.u + 0x7fffu + ((y.u >> 16) & 1u);
  return (ua >> 16) | (ub & 0xffff0000u);
}
__device__ __forceinline__ ushort bf16_1(float x) {  // RNE scalar
  union { float f; uint32 u; } c; c.f = x;
  return (ushort)((c.u + 0x7fffu + ((c.u >> 16) & 1u)) >> 16);
}

union ABu { uint32 u[4]; short8 v; };

// Phase 1: partition edges into 256-node buckets (packed (r<<8)|(c&255))
// and count in-degree (L2-resident 400KB atomics).
__global__ __launch_bounds__(256) void k_part1(const int* __restrict__ ei,
                                               int* __restrict__ bcnt,
                                               int* __restrict__ stage,
                                               int* __restrict__ cnt,
                                               int E, int N, int NB) {
  __shared__ int hist[512];
  __shared__ int gbase[512];
  const int tid = threadIdx.x;
  const int base = blockIdx.x * CHUNK;
  for (int b = tid; b < NB; b += 256) hist[b] = 0;
  __syncthreads();
  int rr[8], cc[8], lp[8];
  #pragma unroll
  for (int j = 0; j < 8; j++) {
    int e = base + tid + j * 256;
    int r = -1, c = -1;
    if (e < E) {
      r = __builtin_nontemporal_load(&ei[e]);
      c = __builtin_nontemporal_load(&ei[(size_t)E + e]);
    }
    bool ok = ((unsigned)r < (unsigned)N) && ((unsigned)c < (unsigned)N);
    rr[j] = ok ? r : -1;
    cc[j] = c;
    lp[j] = ok ? atomicAdd(&hist[c >> BK_SHIFT], 1) : 0;
    if (ok) atomicAdd(&cnt[c], 1);
  }
  __syncthreads();
  for (int b = tid; b < NB; b += 256) {
    int h = hist[b];
    gbase[b] = h ? atomicAdd(&bcnt[b], h) : 0;
  }
  __syncthreads();
  #pragma unroll
  for (int j = 0; j < 8; j++) {
    if (rr[j] >= 0) {
      int b = cc[j] >> BK_SHIFT;
      int pos = gbase[b] + lp[j];
      if (pos < BSTRIDE)
        stage[(size_t)b * BSTRIDE + pos] = (rr[j] << 8) | (cc[j] & 255);
    }
  }
}

// Xh8[s][row][16] = bf16( dinv[row] * (X @ W1)[row, 16s..16s+16) ), slice-major.
// bf16 MFMA 16x16x32; dinv computed inline from cnt. Last block computes
// w = W2@Wfc (128) and c0 = b2.Wfc + bfc (folded k_wc).
__global__ __launch_bounds__(256) void k_gemm(const float* __restrict__ X,
                                              const float* __restrict__ W,
                                              const int* __restrict__ cnt,
                                              ushort* __restrict__ Xh8, int M, int nblk,
                                              const float* __restrict__ W2,
                                              const float* __restrict__ Wfc,
                                              const float* __restrict__ b2,
                                              const float* __restrict__ bfc,
                                              float* __restrict__ wvo,
                                              float* __restrict__ c0) {
  const int tid  = threadIdx.x;
  if (blockIdx.x == nblk) {           // folded k_wc
    if (tid < 128) {
      float s = 0.f;
      #pragma unroll 8
      for (int j = 0; j < 64; j++) s += W2[tid * 64 + j] * Wfc[j];
      wvo[tid] = s;
      if (tid == 0) {
        float cc = 0.f;
        for (int j = 0; j < 64; j++) cc += b2[j] * Wfc[j];
        c0[0] = cc + bfc[0];
      }
    }
    return;
  }
  __shared__ ushort WtT[16384];   // 128 cols x 128 k, swizzled, 32 KB
  const int lane = tid & 63;
  const int wv   = tid >> 6;      // wave 0..3
  const int cl   = lane & 15;
  const int g    = lane >> 4;
  const int rb = blockIdx.x * 64 + wv * 16;
  const size_t SL = (size_t)M * 16;   // ushorts per slice

  // A fragments: per lane row rb+cl, k = 32kk + 8g + j  (j=0..7)
  int rowc = rb + cl; if (rowc >= M) rowc = M - 1;
  const float* xr = X + (size_t)rowc * 128;
  ABu af[4];
  #pragma unroll
  for (int kk = 0; kk < 4; kk++) {
    float4v p = __builtin_nontemporal_load((const float4v*)&xr[kk * 32 + g * 8]);
    float4v q = __builtin_nontemporal_load((const float4v*)&xr[kk * 32 + g * 8 + 4]);
    af[kk].u[0] = pack_bf2(p.x, p.y);
    af[kk].u[1] = pack_bf2(p.z, p.w);
    af[kk].u[2] = pack_bf2(q.x, q.y);
    af[kk].u[3] = pack_bf2(q.z, q.w);
  }

  // dinv for the 4 output rows this lane owns (row = rb + 4g + r)
  float dvr[4];
  #pragma unroll
  for (int r = 0; r < 4; r++) {
    int rw = rb + g * 4 + r; if (rw >= M) rw = M - 1;
    dvr[r] = rsqrtf((float)(cnt[rw] + 1));
  }

  // stage W1 (row-major fp32 [k][c]) -> WtT (transposed swizzled bf16)
  for (int idx = tid; idx < 8192; idx += 256) {
    int k = idx >> 6;
    int c = (idx & 63) * 2;
    float2 w2 = *(const float2*)&W[k * 128 + c];
    int gr = ((k >> 3) ^ ((c & 15) >> 1)) & 15;
    int base = (gr << 4) + (k & 7) * 2;
    *(ushort*)((char*)WtT + c * 256 + base)       = bf16_1(w2.x);
    *(ushort*)((char*)WtT + (c + 1) * 256 + base) = bf16_1(w2.y);
  }
  __syncthreads();

  #pragma unroll
  for (int ct = 0; ct < 8; ct++) {
    const char* wrow = (const char*)WtT + (ct * 16 + cl) * 256;
    f32x4 acc = {0.f, 0.f, 0.f, 0.f};
    #pragma unroll
    for (int kk = 0; kk < 4; kk++) {
      int grn = ((4 * kk + g) ^ (cl >> 1)) & 15;
      short8 bfrag = *(const short8*)(wrow + (grn << 4));
      acc = __builtin_amdgcn_mfma_f32_16x16x32_bf16(af[kk].v, bfrag, acc, 0, 0, 0);
    }
    #pragma unroll
    for (int r = 0; r < 4; r++) {
      int rw = rb + g * 4 + r;
      if (rw < M) Xh8[(size_t)ct * SL + (size_t)rw * 16 + cl] = bf16_1(dvr[r] * acc[r]);
    }
  }
}

// Edge-centric layer-1 aggregation, XCD-sliced: block = (chunk of 768 nodes,
// feature slice s = blockIdx&7 -> pinned to XCD s under round-robin).
// Streams stage buckets, accumulates into LDS (stride-17 padded), epilogue
// fuses self-term + b1 + relu + slice-dot(w) -> atomicAdd(dz).
__global__ __launch_bounds__(1024) void k_aggE(const ushort* __restrict__ Xh8,
                                               const int* __restrict__ stage,
                                               const int* __restrict__ bcnt,
                                               const int* __restrict__ cnt,
                                               const float* __restrict__ b1,
                                               const float* __restrict__ wvv,
                                               float* __restrict__ dz, int M, int N, int NB) {
  __shared__ float acc[ACHUNK * 17];   // 52.2 KB, padded stride vs bank conflicts
  const int tid = threadIdx.x;
  const int s   = blockIdx.x & 7;
  const int ch  = blockIdx.x >> 3;
  const int node0 = ch * ACHUNK;
  for (int i = tid; i < ACHUNK * 17; i += 1024) acc[i] = 0.f;
  __syncthreads();

  const ushort* __restrict__ Xs = Xh8 + (size_t)s * ((size_t)M * 16);
  const int lane_d = tid & 7;          // dword (feature pair) within 32B slice
  const int wid    = tid >> 6;         // wave 0..15

  for (int bk = 0; bk < 3; bk++) {
    int b = ch * 3 + bk;
    if (b >= NB) break;
    int m = bcnt[b]; if (m > BSTRIDE) m = BSTRIDE;
    const int* __restrict__ sb = stage + (size_t)b * BSTRIDE;
    const int boff = (b << BK_SHIFT) - node0;   // local node base of bucket
    for (int e0 = wid * 8; e0 < m; e0 += 128) {
      int e = e0 + ((tid & 63) >> 3);           // edge index for this 8-lane group
      if (e < m) {
        int v = __builtin_nontemporal_load(&sb[e]);
        int r = v >> 8;
        int cl = boff + (v & 255);
        uint32 d = *(const uint32*)(Xs + (size_t)r * 16 + lane_d * 2);
        atomicAdd(&acc[cl * 17 + lane_d * 2 + 0], bf_lo(d));
        atomicAdd(&acc[cl * 17 + lane_d * 2 + 1], bf_hi(d));
      }
    }
  }
  __syncthreads();

  if (tid < ACHUNK) {
    int node = node0 + tid;
    if (node < N) {
      float di = rsqrtf((float)(cnt[node] + 1));
      const uint32* xr = (const uint32*)(Xs + (size_t)node * 16);
      float part = 0.f;
      #pragma unroll
      for (int d = 0; d < 8; d++) {
        uint32 u = xr[d];                        // self-loop term
        float a0 = acc[tid * 17 + 2 * d]     + bf_lo(u);
        float a1 = acc[tid * 17 + 2 * d + 1] + bf_hi(u);
        float h0 = fmaxf(fmaf(di, a0, b1[s * 16 + 2 * d]), 0.f);
        float h1 = fmaxf(fmaf(di, a1, b1[s * 16 + 2 * d + 1]), 0.f);
        part = fmaf(h0, wvv[s * 16 + 2 * d], part);
        part = fmaf(h1, wvv[s * 16 + 2 * d + 1], part);
      }
      atomicAdd(&dz[node], di * part);
    }
  }
}

// Edge-centric layer 2: out[i] = c0 + dinv[i] * (dz[i] + sum_in dz[src]).
// One block per 2048-node chunk (8 buckets), scalar LDS accumulation.
__global__ __launch_bounds__(1024) void k_out2(const float* __restrict__ dz,
                                               const int* __restrict__ stage,
                                               const int* __restrict__ bcnt,
                                               const int* __restrict__ cnt,
                                               const float* __restrict__ c0,
                                               float* __restrict__ out, int N, int NB) {
  __shared__ float acc[OCHUNK];   // 8 KB
  const int tid = threadIdx.x;
  const int ch  = blockIdx.x;
  const int node0 = ch * OCHUNK;
  for (int i = tid; i < OCHUNK; i += 1024) acc[i] = 0.f;
  __syncthreads();
  for (int bk = 0; bk < 8; bk++) {
    int b = ch * 8 + bk;
    if (b >= NB) break;
    int m = bcnt[b]; if (m > BSTRIDE) m = BSTRIDE;
    const int* __restrict__ sb = stage + (size_t)b * BSTRIDE;
    const int boff = (b << BK_SHIFT) - node0;
    for (int e = tid; e < m; e += 1024) {
      int v = __builtin_nontemporal_load(&sb[e]);
      atomicAdd(&acc[boff + (v & 255)], dz[v >> 8]);
    }
  }
  __syncthreads();
  for (int i = tid; i < OCHUNK; i += 1024) {
    int node = node0 + i;
    if (node < N) {
      float di = rsqrtf((float)(cnt[node] + 1));
      out[node] = c0[0] + di * (dz[node] + acc[i]);
    }
  }
}

extern "C" void kernel_launch(void* const* d_in, const int* in_sizes, int n_in,
                              void* d_out, int out_size, void* d_ws, size_t ws_size,
                              hipStream_t stream) {
  const float* x   = (const float*)d_in[0];
  const int*   ei  = (const int*)d_in[1];   // int inputs arrive as int32
  // d_in[2] edge_weight: unused by reference
  const float* W1  = (const float*)d_in[3];
  const float* b1  = (const float*)d_in[4];
  const float* W2  = (const float*)d_in[5];
  const float* b2  = (const float*)d_in[6];
  const float* Wfc = (const float*)d_in[7];
  const float* bfc = (const float*)d_in[8];
  float* out = (float*)d_out;

  const int N = in_sizes[0] / 128;   // 100000
  const int E = in_sizes[1] / 2;     // 1600000
  const int NB = (N + 255) >> 8;     // 391 buckets

  // workspace layout (~39.2 MB)
  char* ws = (char*)d_ws;
  ushort* Xh8 = (ushort*)(ws);                              // [8][N][16] bf16, 25.6MB
  size_t off = (size_t)N * 256;
  int* stage = (int*)(ws + off); off += (size_t)NB * BSTRIDE * 4;  // 12.81MB
  int* cnt   = (int*)(ws + off); off += (size_t)N * 4;
  float* dz  = (float*)(ws + off); off += (size_t)N * 4;
  int* bcnt  = (int*)(ws + off); off += (size_t)NB * 4;
  float* wv  = (float*)(ws + off); off += 512;
  float* c0  = (float*)(ws + off);

  // zero cnt + dz + bcnt in one shot (contiguous)
  hipMemsetAsync(cnt, 0, (size_t)(2 * N + NB) * 4, stream);

  hipLaunchKernelGGL(k_part1, dim3((E + CHUNK - 1) / CHUNK), dim3(256), 0, stream,
                     ei, bcnt, stage, cnt, E, N, NB);

  const int nblk = (N + 63) / 64;
  hipLaunchKernelGGL(k_gemm, dim3(nblk + 1), dim3(256), 0, stream,
                     x, W1, cnt, Xh8, N, nblk, W2, Wfc, b2, bfc, wv, c0);

  const int nch = (N + ACHUNK - 1) / ACHUNK;   // 131
  hipLaunchKernelGGL(k_aggE, dim3(nch * 8), dim3(1024), 0, stream,
                     Xh8, stage, bcnt, cnt, b1, wv, dz, N, N, NB);

  hipLaunchKernelGGL(k_out2, dim3((N + OCHUNK - 1) / OCHUNK), dim3(1024), 0, stream,
                     dz, stage, bcnt, cnt, c0, out, N, NB);
}

// Round 11
// 222.143 us; speedup vs baseline: 6.4041x; 6.4041x over previous
//
#include <hip/hip_runtime.h>
#include <cstddef>

#define CAP 64
#define BK_SHIFT 8      // 256 nodes per bucket
#define BSTRIDE 8192    // staging slots per bucket (max load ~4400)
#define CHUNK 2048      // edges per workgroup in k_part1 (256 thr x 8)

typedef unsigned int uint32;
typedef unsigned short ushort;
typedef __attribute__((ext_vector_type(8))) short short8;
typedef __attribute__((ext_vector_type(4))) float f32x4;
typedef __attribute__((ext_vector_type(4))) int int4v;
typedef __attribute__((ext_vector_type(4))) float float4v;

__device__ __forceinline__ float bf_lo(uint32 v) {
  union { uint32 u; float f; } c; c.u = v << 16; return c.f;
}
__device__ __forceinline__ float bf_hi(uint32 v) {
  union { uint32 u; float f; } c; c.u = v & 0xffff0000u; return c.f;
}
__device__ __forceinline__ uint32 pack_bf2(float a, float b) {  // RNE
  union { float f; uint32 u; } x, y; x.f = a; y.f = b;
  uint32 ua = x.u + 0x7fffu + ((x.u >> 16) & 1u);
  uint32 ub = y.u + 0x7fffu + ((y.u >> 16) & 1u);
  return (ua >> 16) | (ub & 0xffff0000u);
}
__device__ __forceinline__ ushort bf16_1(float x) {  // RNE scalar
  union { float f; uint32 u; } c; c.f = x;
  return (ushort)((c.u + 0x7fffu + ((c.u >> 16) & 1u)) >> 16);
}

union ABu { uint32 u[4]; short8 v; };

// Phase 1: partition edges into 256-node buckets (packed (r<<8)|(c&255)).
__global__ __launch_bounds__(256) void k_part1(const int* __restrict__ ei,
                                               int* __restrict__ bcnt,
                                               int* __restrict__ stage,
                                               int E, int N, int NB) {
  __shared__ int hist[512];
  __shared__ int gbase[512];
  const int tid = threadIdx.x;
  const int base = blockIdx.x * CHUNK;
  for (int b = tid; b < NB; b += 256) hist[b] = 0;
  __syncthreads();
  int rr[8], cc[8], lp[8];
  #pragma unroll
  for (int j = 0; j < 8; j++) {
    int e = base + tid + j * 256;
    int r = -1, c = -1;
    if (e < E) {
      r = __builtin_nontemporal_load(&ei[e]);
      c = __builtin_nontemporal_load(&ei[(size_t)E + e]);
    }
    bool ok = ((unsigned)r < (unsigned)N) && ((unsigned)c < (unsigned)N);
    rr[j] = ok ? r : -1;
    cc[j] = c;
    lp[j] = ok ? atomicAdd(&hist[c >> BK_SHIFT], 1) : 0;
  }
  __syncthreads();
  for (int b = tid; b < NB; b += 256) {
    int h = hist[b];
    gbase[b] = h ? atomicAdd(&bcnt[b], h) : 0;
  }
  __syncthreads();
  #pragma unroll
  for (int j = 0; j < 8; j++) {
    if (rr[j] >= 0) {
      int b = cc[j] >> BK_SHIFT;
      int pos = gbase[b] + lp[j];
      if (pos < BSTRIDE)
        stage[(size_t)b * BSTRIDE + pos] = (rr[j] << 8) | (cc[j] & 255);
    }
  }
}

// Phase 2: one workgroup per bucket; csr writes confined to a 64KB window.
// Slots [deg, round8(deg)) padded with the node's own index (tail-free
// downstream loops). Block NB computes w = W2@Wfc and c0 (folded k_wc).
__global__ __launch_bounds__(256) void k_fill2(const int* __restrict__ stage,
                                               const int* __restrict__ bcnt,
                                               int* __restrict__ csr,
                                               int* __restrict__ cnt, int N, int NB,
                                               const float* __restrict__ W2,
                                               const float* __restrict__ Wfc,
                                               const float* __restrict__ b2,
                                               const float* __restrict__ bfc,
                                               float* __restrict__ wvo,
                                               float* __restrict__ c0) {
  const int b = blockIdx.x;
  const int tid = threadIdx.x;
  if (b == NB) {                      // folded k_wc
    if (tid < 128) {
      float s = 0.f;
      #pragma unroll 8
      for (int j = 0; j < 64; j++) s += W2[tid * 64 + j] * Wfc[j];
      wvo[tid] = s;
      if (tid == 0) {
        float cc = 0.f;
        for (int j = 0; j < 64; j++) cc += b2[j] * Wfc[j];
        c0[0] = cc + bfc[0];
      }
    }
    return;
  }
  __shared__ int lc[256];
  lc[tid] = 0;
  __syncthreads();
  int m = bcnt[b]; if (m > BSTRIDE) m = BSTRIDE;
  const int node0 = b << BK_SHIFT;
  const int* __restrict__ sb = stage + (size_t)b * BSTRIDE;
  for (int e = tid; e < m; e += 256) {
    int v = __builtin_nontemporal_load(&sb[e]);
    int cl = v & 255;
    int r = v >> 8;
    int pos = atomicAdd(&lc[cl], 1);
    if (pos < CAP) csr[(size_t)(node0 + cl) * CAP + pos] = r;
  }
  __syncthreads();
  int node = node0 + tid;
  if (node < N) {
    int d = lc[tid]; if (d > CAP) d = CAP;
    cnt[node] = d;
    int d8 = (d + 7) & ~7; if (d8 > CAP) d8 = CAP;
    for (int p = d; p < d8; p++) csr[(size_t)node * CAP + p] = node;  // self-pad
  }
}

// Xh8[s][row][16] = bf16( dinv[row] * (X @ W1)[row, 16s..16s+16) ), slice-major.
__global__ __launch_bounds__(256) void k_gemm(const float* __restrict__ X,
                                              const float* __restrict__ W,
                                              const int* __restrict__ cnt,
                                              ushort* __restrict__ Xh8, int M) {
  __shared__ ushort WtT[16384];   // 128 cols x 128 k, swizzled, 32 KB
  const int tid  = threadIdx.x;
  const int lane = tid & 63;
  const int wv   = tid >> 6;      // wave 0..3
  const int cl   = lane & 15;
  const int g    = lane >> 4;
  const int rb = blockIdx.x * 64 + wv * 16;
  const size_t SL = (size_t)M * 16;   // ushorts per slice

  int rowc = rb + cl; if (rowc >= M) rowc = M - 1;
  const float* xr = X + (size_t)rowc * 128;
  ABu af[4];
  #pragma unroll
  for (int kk = 0; kk < 4; kk++) {
    float4v p = __builtin_nontemporal_load((const float4v*)&xr[kk * 32 + g * 8]);
    float4v q = __builtin_nontemporal_load((const float4v*)&xr[kk * 32 + g * 8 + 4]);
    af[kk].u[0] = pack_bf2(p.x, p.y);
    af[kk].u[1] = pack_bf2(p.z, p.w);
    af[kk].u[2] = pack_bf2(q.x, q.y);
    af[kk].u[3] = pack_bf2(q.z, q.w);
  }

  float dvr[4];
  #pragma unroll
  for (int r = 0; r < 4; r++) {
    int rw = rb + g * 4 + r; if (rw >= M) rw = M - 1;
    dvr[r] = rsqrtf((float)(cnt[rw] + 1));
  }

  for (int idx = tid; idx < 8192; idx += 256) {
    int k = idx >> 6;
    int c = (idx & 63) * 2;
    float2 w2 = *(const float2*)&W[k * 128 + c];
    int gr = ((k >> 3) ^ ((c & 15) >> 1)) & 15;
    int base = (gr << 4) + (k & 7) * 2;
    *(ushort*)((char*)WtT + c * 256 + base)       = bf16_1(w2.x);
    *(ushort*)((char*)WtT + (c + 1) * 256 + base) = bf16_1(w2.y);
  }
  __syncthreads();

  #pragma unroll
  for (int ct = 0; ct < 8; ct++) {
    const char* wrow = (const char*)WtT + (ct * 16 + cl) * 256;
    f32x4 acc = {0.f, 0.f, 0.f, 0.f};
    #pragma unroll
    for (int kk = 0; kk < 4; kk++) {
      int grn = ((4 * kk + g) ^ (cl >> 1)) & 15;
      short8 bfrag = *(const short8*)(wrow + (grn << 4));
      acc = __builtin_amdgcn_mfma_f32_16x16x32_bf16(af[kk].v, bfrag, acc, 0, 0, 0);
    }
    #pragma unroll
    for (int r = 0; r < 4; r++) {
      int rw = rb + g * 4 + r;
      if (rw < M) Xh8[(size_t)ct * SL + (size_t)rw * 16 + cl] = bf16_1(dvr[r] * acc[r]);
    }
  }
}

// XCD-sliced gather aggregation: block = (32-node chunk, slice s=blockIdx&7).
// 8-lane group per node; csr loaded 8-wide per group, src ids spread via
// __shfl; 32B sub-row gathers hit the XCD-resident 3.2MB slice in L2.
// Race-free partials: dzp[s][i] = slice-dot; no atomics anywhere.
__global__ __launch_bounds__(256) void k_agg1s(const ushort* __restrict__ Xh8,
                                               const int* __restrict__ csr,
                                               const int* __restrict__ cnt,
                                               const float* __restrict__ b1,
                                               const float* __restrict__ wvv,
                                               float* __restrict__ dzp, int M, int N) {
  const int tid  = threadIdx.x;
  const int s    = blockIdx.x & 7;
  const int chnk = blockIdx.x >> 3;
  const int lane = tid & 63;
  const int ld   = lane & 7;                       // lane within group
  const int i    = chnk * 32 + (tid >> 6) * 8 + (lane >> 3);
  if (i >= N) return;
  const uint32* __restrict__ Xs = (const uint32*)(Xh8 + (size_t)s * (size_t)M * 16);

  int deg = cnt[i]; if (deg > CAP) deg = CAP;
  const int deg8 = (deg + 7) & ~7;
  const float di = rsqrtf((float)(deg + 1));

  float ax = 0.f, ay = 0.f;
  for (int base = 0; base < deg8; base += 8) {
    int ereg = __builtin_nontemporal_load(&csr[(size_t)i * CAP + base + ld]);
    #pragma unroll
    for (int j = 0; j < 8; j++) {
      int src = __shfl(ereg, (lane & 56) + j, 64);   // group-uniform src
      uint32 u = Xs[(size_t)src * 8 + ld];
      ax += bf_lo(u); ay += bf_hi(u);
    }
  }
  uint32 su = Xs[(size_t)i * 8 + ld];                // self-loop row
  const float selfc = 1.0f - (float)(deg8 - deg);    // undo padded self adds
  ax = fmaf(selfc, bf_lo(su), ax);
  ay = fmaf(selfc, bf_hi(su), ay);

  int f = s * 16 + 2 * ld;
  float h0 = fmaxf(fmaf(di, ax, b1[f]), 0.f);
  float h1 = fmaxf(fmaf(di, ay, b1[f + 1]), 0.f);
  float part = fmaf(h0, wvv[f], h1 * wvv[f + 1]);
  part += __shfl_xor(part, 1, 64);
  part += __shfl_xor(part, 2, 64);
  part += __shfl_xor(part, 4, 64);
  if (ld == 0) dzp[(size_t)s * N + i] = part;        // di applied in k_red
}

// dz[i] = dinv[i] * sum_s dzp[s][i]
__global__ __launch_bounds__(256) void k_red(const float* __restrict__ dzp,
                                             const int* __restrict__ cnt,
                                             float* __restrict__ dz, int N) {
  int i = blockIdx.x * 256 + threadIdx.x;
  if (i >= N) return;
  float s = 0.f;
  #pragma unroll
  for (int k = 0; k < 8; k++) s += dzp[(size_t)k * N + i];
  dz[i] = rsqrtf((float)(cnt[i] + 1)) * s;
}

// out[i] = c0 + dinv[i] * (dz[i] + sum_in dz[src]); int4 csr loads over the
// self-padded deg8 range, padding corrected via (1 - npad) * dz[i].
__global__ __launch_bounds__(256) void k_out(const float* __restrict__ dz,
                                             const int* __restrict__ csr,
                                             const int* __restrict__ cnt,
                                             const float* __restrict__ c0,
                                             float* __restrict__ out, int N) {
  int i = blockIdx.x * 256 + threadIdx.x;
  if (i >= N) return;
  int deg = cnt[i]; if (deg > CAP) deg = CAP;
  const int deg8 = (deg + 7) & ~7;
  const int4v* __restrict__ edges = (const int4v*)(csr + (size_t)i * CAP);
  float s0 = (1.0f - (float)(deg8 - deg)) * dz[i];
  float s1 = 0.f, s2 = 0.f, s3 = 0.f;
  for (int e4 = 0; e4 < (deg8 >> 2); e4 += 2) {
    int4v q0 = __builtin_nontemporal_load(&edges[e4]);
    int4v q1 = __builtin_nontemporal_load(&edges[e4 + 1]);
    s0 += dz[q0.x]; s1 += dz[q0.y]; s2 += dz[q0.z]; s3 += dz[q0.w];
    s0 += dz[q1.x]; s1 += dz[q1.y]; s2 += dz[q1.z]; s3 += dz[q1.w];
  }
  out[i] = rsqrtf((float)(cnt[i] + 1)) * ((s0 + s1) + (s2 + s3)) + c0[0];
}

extern "C" void kernel_launch(void* const* d_in, const int* in_sizes, int n_in,
                              void* d_out, int out_size, void* d_ws, size_t ws_size,
                              hipStream_t stream) {
  const float* x   = (const float*)d_in[0];
  const int*   ei  = (const int*)d_in[1];   // int inputs arrive as int32
  // d_in[2] edge_weight: unused by reference
  const float* W1  = (const float*)d_in[3];
  const float* b1  = (const float*)d_in[4];
  const float* W2  = (const float*)d_in[5];
  const float* b2  = (const float*)d_in[6];
  const float* Wfc = (const float*)d_in[7];
  const float* bfc = (const float*)d_in[8];
  float* out = (float*)d_out;

  const int N = in_sizes[0] / 128;   // 100000
  const int E = in_sizes[1] / 2;     // 1600000
  const int NB = (N + 255) >> 8;     // 391 buckets

  // workspace layout (~65 MB; harness ws proven >= 78 MB by earlier rounds)
  char* ws = (char*)d_ws;
  ushort* Xh8 = (ushort*)(ws);                              // [8][N][16] bf16, 25.6MB
  size_t off = (size_t)N * 256;
  int* csr   = (int*)(ws + off); off += (size_t)N * 256;    // 25.6MB
  int* stage = (int*)(ws + off);                            // 12.81MB
  float* dzp = (float*)stage;                               // aliases stage (3.2MB), after fill2
  off += (size_t)NB * BSTRIDE * 4;
  int* cnt   = (int*)(ws + off); off += (size_t)N * 4;
  float* dz  = (float*)(ws + off); off += (size_t)N * 4;
  int* bcnt  = (int*)(ws + off); off += (size_t)NB * 4;
  float* wv  = (float*)(ws + off); off += 512;
  float* c0  = (float*)(ws + off);

  hipMemsetAsync(bcnt, 0, (size_t)NB * 4, stream);
  hipLaunchKernelGGL(k_part1, dim3((E + CHUNK - 1) / CHUNK), dim3(256), 0, stream,
                     ei, bcnt, stage, E, N, NB);
  hipLaunchKernelGGL(k_fill2, dim3(NB + 1), dim3(256), 0, stream,
                     stage, bcnt, csr, cnt, N, NB, W2, Wfc, b2, bfc, wv, c0);
  hipLaunchKernelGGL(k_gemm,  dim3((N + 63) / 64), dim3(256), 0, stream,
                     x, W1, cnt, Xh8, N);
  hipLaunchKernelGGL(k_agg1s, dim3(((N + 31) / 32) * 8), dim3(256), 0, stream,
                     Xh8, csr, cnt, b1, wv, dzp, N, N);
  hipLaunchKernelGGL(k_red,   dim3((N + 255) / 256), dim3(256), 0, stream,
                     dzp, cnt, dz, N);
  hipLaunchKernelGGL(k_out,   dim3((N + 255) / 256), dim3(256), 0, stream,
                     dz, csr, cnt, c0, out, N);
}

// Round 12
// 209.045 us; speedup vs baseline: 6.8053x; 1.0627x over previous
//
#include <hip/hip_runtime.h>
#include <cstddef>

#define CAP 64
#define BK_SHIFT 8      // 256 nodes per bucket
#define BSTRIDE 8192    // staging slots per bucket (max load ~4400)
#define CHUNK 2048      // edges per workgroup in k_part1 (256 thr x 8)

typedef unsigned int uint32;
typedef unsigned short ushort;
typedef __attribute__((ext_vector_type(8))) short short8;
typedef __attribute__((ext_vector_type(4))) float f32x4;
typedef __attribute__((ext_vector_type(4))) int int4v;
typedef __attribute__((ext_vector_type(4))) float float4v;

__device__ __forceinline__ float bf_lo(uint32 v) {
  union { uint32 u; float f; } c; c.u = v << 16; return c.f;
}
__device__ __forceinline__ float bf_hi(uint32 v) {
  union { uint32 u; float f; } c; c.u = v & 0xffff0000u; return c.f;
}
__device__ __forceinline__ uint32 pack_bf2(float a, float b) {  // RNE
  union { float f; uint32 u; } x, y; x.f = a; y.f = b;
  uint32 ua = x.u + 0x7fffu + ((x.u >> 16) & 1u);
  uint32 ub = y.u + 0x7fffu + ((y.u >> 16) & 1u);
  return (ua >> 16) | (ub & 0xffff0000u);
}
__device__ __forceinline__ ushort bf16_1(float x) {  // RNE scalar
  union { float f; uint32 u; } c; c.f = x;
  return (ushort)((c.u + 0x7fffu + ((c.u >> 16) & 1u)) >> 16);
}

union ABu { uint32 u[4]; short8 v; };

// Phase 1: partition edges into 256-node buckets (packed (r<<8)|(c&255)),
// count in-degree via L2-resident atomics (400KB). Vectorized int4 loads.
__global__ __launch_bounds__(256) void k_part1(const int* __restrict__ ei,
                                               int* __restrict__ bcnt,
                                               int* __restrict__ stage,
                                               int* __restrict__ cnt,
                                               int E, int N, int NB) {
  __shared__ int hist[512];
  __shared__ int gbase[512];
  const int tid = threadIdx.x;
  const int base = blockIdx.x * CHUNK;
  for (int b = tid; b < NB; b += 256) hist[b] = 0;
  __syncthreads();
  int rr[8], cc[8], lp[8];
  #pragma unroll
  for (int h = 0; h < 2; h++) {                 // two int4 rounds of 1024 edges
    int e0 = base + h * 1024 + tid * 4;
    int4v r4 = {-1, -1, -1, -1}, c4 = {-1, -1, -1, -1};
    if (e0 + 3 < E) {
      r4 = __builtin_nontemporal_load((const int4v*)&ei[e0]);
      c4 = __builtin_nontemporal_load((const int4v*)&ei[(size_t)E + e0]);
    } else {
      for (int j = 0; j < 4; j++)
        if (e0 + j < E) {
          ((int*)&r4)[j] = ei[e0 + j];
          ((int*)&c4)[j] = ei[(size_t)E + e0 + j];
        }
    }
    #pragma unroll
    for (int j = 0; j < 4; j++) {
      int r = ((int*)&r4)[j], c = ((int*)&c4)[j];
      bool ok = ((unsigned)r < (unsigned)N) && ((unsigned)c < (unsigned)N);
      rr[h * 4 + j] = ok ? r : -1;
      cc[h * 4 + j] = c;
      lp[h * 4 + j] = ok ? atomicAdd(&hist[c >> BK_SHIFT], 1) : 0;
      if (ok) atomicAdd(&cnt[c], 1);
    }
  }
  __syncthreads();
  for (int b = tid; b < NB; b += 256) {
    int h = hist[b];
    gbase[b] = h ? atomicAdd(&bcnt[b], h) : 0;
  }
  __syncthreads();
  #pragma unroll
  for (int j = 0; j < 8; j++) {
    if (rr[j] >= 0) {
      int b = cc[j] >> BK_SHIFT;
      int pos = gbase[b] + lp[j];
      if (pos < BSTRIDE)
        stage[(size_t)b * BSTRIDE + pos] = (rr[j] << 8) | (cc[j] & 255);
    }
  }
}

// Fused build: blocks [0,NB) = csr fill (64KB-window scatter, self-padded);
// blocks [NB, NB+ngemm) = bf16-MFMA GEMM with dinv folded (cnt ready from
// part1); last block = w = W2@Wfc, c0. Fill (LDS/scatter-bound) overlaps
// GEMM (MFMA-bound) on different CUs within one launch.
__global__ __launch_bounds__(256) void k_build(const int* __restrict__ stage,
                                               const int* __restrict__ bcnt,
                                               int* __restrict__ csr,
                                               const int* __restrict__ cnt,
                                               const float* __restrict__ X,
                                               const float* __restrict__ W,
                                               ushort* __restrict__ Xh,
                                               int M, int NB, int ngemm,
                                               const float* __restrict__ W2,
                                               const float* __restrict__ Wfc,
                                               const float* __restrict__ b2,
                                               const float* __restrict__ bfc,
                                               float* __restrict__ wvo,
                                               float* __restrict__ c0) {
  __shared__ ushort WtT[16384];   // gemm: 128x128 swizzled bf16 (32KB)
  __shared__ int lc[256];         // fill: per-node counters
  const int tid = threadIdx.x;
  const int bx  = blockIdx.x;

  if (bx < NB) {                  // ---- csr fill part ----
    lc[tid] = 0;
    __syncthreads();
    int m = bcnt[bx]; if (m > BSTRIDE) m = BSTRIDE;
    const int node0 = bx << BK_SHIFT;
    const int* __restrict__ sb = stage + (size_t)bx * BSTRIDE;
    int e = tid * 4;
    for (; e + 3 < m; e += 1024) {
      int4v v4 = __builtin_nontemporal_load((const int4v*)&sb[e]);
      #pragma unroll
      for (int j = 0; j < 4; j++) {
        int v = ((int*)&v4)[j];
        int pos = atomicAdd(&lc[v & 255], 1);
        if (pos < CAP) csr[(size_t)(node0 + (v & 255)) * CAP + pos] = v >> 8;
      }
    }
    for (int ee = e; ee < m; ee++) {        // tail < 4 per thread-slot
      if ((ee & 3) == 0 || ee == e) {}      // keep simple: scalar
      int v = sb[ee];
      // only threads whose vector slot covered the tail region duplicate work;
      // restrict: let thread 0 of the last slot handle remaining serially
      (void)v;
      break;
    }
    // handle tail correctly: m % 4 leftover edges done by thread 255
    if (tid == 255) {
      int mt = m & ~3;
      int estart = mt;
      // only process if the vector loop's grid didn't cover [mt, m)
      for (int ee = estart; ee < m; ee++) {
        int v = sb[ee];
        int pos = atomicAdd(&lc[v & 255], 1);
        if (pos < CAP) csr[(size_t)(node0 + (v & 255)) * CAP + pos] = v >> 8;
      }
    }
    __syncthreads();
    int node = node0 + tid;
    if (node < M) {
      int d = lc[tid]; if (d > CAP) d = CAP;
      int d8 = (d + 7) & ~7; if (d8 > CAP) d8 = CAP;
      for (int p = d; p < d8; p++) csr[(size_t)node * CAP + p] = node;  // self-pad
    }
    return;
  }

  if (bx == NB + ngemm) {         // ---- folded k_wc ----
    if (tid < 128) {
      float s = 0.f;
      #pragma unroll 8
      for (int j = 0; j < 64; j++) s += W2[tid * 64 + j] * Wfc[j];
      wvo[tid] = s;
      if (tid == 0) {
        float cc = 0.f;
        for (int j = 0; j < 64; j++) cc += b2[j] * Wfc[j];
        c0[0] = cc + bfc[0];
      }
    }
    return;
  }

  // ---- gemm part: Xh = bf16(dinv * X@W1), MFMA 16x16x32 ----
  const int lane = tid & 63;
  const int wv   = tid >> 6;
  const int cl   = lane & 15;
  const int g    = lane >> 4;
  const int rb = (bx - NB) * 64 + wv * 16;

  int rowc = rb + cl; if (rowc >= M) rowc = M - 1;
  const float* xr = X + (size_t)rowc * 128;
  ABu af[4];
  #pragma unroll
  for (int kk = 0; kk < 4; kk++) {
    float4v p = __builtin_nontemporal_load((const float4v*)&xr[kk * 32 + g * 8]);
    float4v q = __builtin_nontemporal_load((const float4v*)&xr[kk * 32 + g * 8 + 4]);
    af[kk].u[0] = pack_bf2(p.x, p.y);
    af[kk].u[1] = pack_bf2(p.z, p.w);
    af[kk].u[2] = pack_bf2(q.x, q.y);
    af[kk].u[3] = pack_bf2(q.z, q.w);
  }

  float dvr[4];
  #pragma unroll
  for (int r = 0; r < 4; r++) {
    int rw = rb + g * 4 + r; if (rw >= M) rw = M - 1;
    dvr[r] = rsqrtf((float)(cnt[rw] + 1));
  }

  for (int idx = tid; idx < 8192; idx += 256) {
    int k = idx >> 6;
    int c = (idx & 63) * 2;
    float2 w2 = *(const float2*)&W[k * 128 + c];
    int gr = ((k >> 3) ^ ((c & 15) >> 1)) & 15;
    int base = (gr << 4) + (k & 7) * 2;
    *(ushort*)((char*)WtT + c * 256 + base)       = bf16_1(w2.x);
    *(ushort*)((char*)WtT + (c + 1) * 256 + base) = bf16_1(w2.y);
  }
  __syncthreads();

  #pragma unroll
  for (int ct = 0; ct < 8; ct++) {
    const char* wrow = (const char*)WtT + (ct * 16 + cl) * 256;
    f32x4 acc = {0.f, 0.f, 0.f, 0.f};
    #pragma unroll
    for (int kk = 0; kk < 4; kk++) {
      int grn = ((4 * kk + g) ^ (cl >> 1)) & 15;
      short8 bfrag = *(const short8*)(wrow + (grn << 4));
      acc = __builtin_amdgcn_mfma_f32_16x16x32_bf16(af[kk].v, bfrag, acc, 0, 0, 0);
    }
    #pragma unroll
    for (int r = 0; r < 4; r++) {
      int rw = rb + g * 4 + r;
      if (rw < M) Xh[(size_t)rw * 128 + ct * 16 + cl] = bf16_1(dvr[r] * acc[r]);
    }
  }
}

// One wave per node; tail-free unroll-8 gather over pre-scaled bf16 rows.
__global__ __launch_bounds__(256) void k_agg1(const uint32* __restrict__ Xh,
                                              const int* __restrict__ csr,
                                              const int* __restrict__ cnt,
                                              const float* __restrict__ b1,
                                              const float* __restrict__ wv,
                                              float* __restrict__ dz, int N) {
  int wid = (blockIdx.x * 256 + threadIdx.x) >> 6;
  int lane = threadIdx.x & 63;
  if (wid >= N) return;
  const int i = wid;
  int cv = cnt[i];
  int deg = cv; if (deg > CAP) deg = CAP;
  const int deg8 = (deg + 7) & ~7;
  const float di = rsqrtf((float)(cv + 1));
  int edge_reg = i;
  if (lane < deg8) edge_reg = __builtin_nontemporal_load(&csr[(size_t)i * CAP + lane]);

  uint32 vs = Xh[(size_t)i * 64 + lane];          // self-loop row
  float a0x = 0.f, a0y = 0.f, a1x = 0.f, a1y = 0.f;
  float a2x = 0.f, a2y = 0.f, a3x = 0.f, a3y = 0.f;
  float a4x = 0.f, a4y = 0.f, a5x = 0.f, a5y = 0.f;
  float a6x = 0.f, a6y = 0.f, a7x = 0.f, a7y = 0.f;

  for (int e = 0; e < deg8; e += 8) {
    int s0 = __builtin_amdgcn_readlane(edge_reg, e + 0);
    int s1 = __builtin_amdgcn_readlane(edge_reg, e + 1);
    int s2 = __builtin_amdgcn_readlane(edge_reg, e + 2);
    int s3 = __builtin_amdgcn_readlane(edge_reg, e + 3);
    int s4 = __builtin_amdgcn_readlane(edge_reg, e + 4);
    int s5 = __builtin_amdgcn_readlane(edge_reg, e + 5);
    int s6 = __builtin_amdgcn_readlane(edge_reg, e + 6);
    int s7 = __builtin_amdgcn_readlane(edge_reg, e + 7);
    uint32 v0 = Xh[(size_t)s0 * 64 + lane];
    uint32 v1 = Xh[(size_t)s1 * 64 + lane];
    uint32 v2 = Xh[(size_t)s2 * 64 + lane];
    uint32 v3 = Xh[(size_t)s3 * 64 + lane];
    uint32 v4 = Xh[(size_t)s4 * 64 + lane];
    uint32 v5 = Xh[(size_t)s5 * 64 + lane];
    uint32 v6 = Xh[(size_t)s6 * 64 + lane];
    uint32 v7 = Xh[(size_t)s7 * 64 + lane];
    a0x += bf_lo(v0); a0y += bf_hi(v0);
    a1x += bf_lo(v1); a1y += bf_hi(v1);
    a2x += bf_lo(v2); a2y += bf_hi(v2);
    a3x += bf_lo(v3); a3y += bf_hi(v3);
    a4x += bf_lo(v4); a4y += bf_hi(v4);
    a5x += bf_lo(v5); a5y += bf_hi(v5);
    a6x += bf_lo(v6); a6y += bf_hi(v6);
    a7x += bf_lo(v7); a7y += bf_hi(v7);
  }
  const float selfc = 1.0f - (float)(deg8 - deg);
  float sx = ((a0x + a1x) + (a2x + a3x)) + ((a4x + a5x) + (a6x + a7x));
  float sy = ((a0y + a1y) + (a2y + a3y)) + ((a4y + a5y) + (a6y + a7y));
  sx = fmaf(selfc, bf_lo(vs), sx);
  sy = fmaf(selfc, bf_hi(vs), sy);

  float2 bb = *(const float2*)&b1[lane * 2];
  float h0 = fmaxf(fmaf(di, sx, bb.x), 0.f);
  float h1 = fmaxf(fmaf(di, sy, bb.y), 0.f);
  float2 ww = *(const float2*)&wv[lane * 2];
  float part = fmaf(h0, ww.x, h1 * ww.y);
  #pragma unroll
  for (int m = 32; m > 0; m >>= 1) part += __shfl_xor(part, m, 64);
  if (lane == 0) dz[i] = di * part;
}

// out[i] = c0 + dinv[i] * (dz[i] + sum_in dz[src]); int4 csr loads over the
// self-padded deg8 range, padding corrected via (1 - npad) * dz[i].
__global__ __launch_bounds__(256) void k_out(const float* __restrict__ dz,
                                             const int* __restrict__ csr,
                                             const int* __restrict__ cnt,
                                             const float* __restrict__ c0,
                                             float* __restrict__ out, int N) {
  int i = blockIdx.x * 256 + threadIdx.x;
  if (i >= N) return;
  int cv = cnt[i];
  int deg = cv; if (deg > CAP) deg = CAP;
  const int deg8 = (deg + 7) & ~7;
  const int4v* __restrict__ edges = (const int4v*)(csr + (size_t)i * CAP);
  float s0 = (1.0f - (float)(deg8 - deg)) * dz[i];
  float s1 = 0.f, s2 = 0.f, s3 = 0.f;
  for (int e4 = 0; e4 < (deg8 >> 2); e4 += 2) {
    int4v q0 = __builtin_nontemporal_load(&edges[e4]);
    int4v q1 = __builtin_nontemporal_load(&edges[e4 + 1]);
    s0 += dz[q0.x]; s1 += dz[q0.y]; s2 += dz[q0.z]; s3 += dz[q0.w];
    s0 += dz[q1.x]; s1 += dz[q1.y]; s2 += dz[q1.z]; s3 += dz[q1.w];
  }
  out[i] = rsqrtf((float)(cv + 1)) * ((s0 + s1) + (s2 + s3)) + c0[0];
}

extern "C" void kernel_launch(void* const* d_in, const int* in_sizes, int n_in,
                              void* d_out, int out_size, void* d_ws, size_t ws_size,
                              hipStream_t stream) {
  const float* x   = (const float*)d_in[0];
  const int*   ei  = (const int*)d_in[1];   // int inputs arrive as int32
  // d_in[2] edge_weight: unused by reference
  const float* W1  = (const float*)d_in[3];
  const float* b1  = (const float*)d_in[4];
  const float* W2  = (const float*)d_in[5];
  const float* b2  = (const float*)d_in[6];
  const float* Wfc = (const float*)d_in[7];
  const float* bfc = (const float*)d_in[8];
  float* out = (float*)d_out;

  const int N = in_sizes[0] / 128;   // 100000
  const int E = in_sizes[1] / 2;     // 1600000
  const int NB = (N + 255) >> 8;     // 391 buckets

  // workspace layout (~65 MB)
  char* ws = (char*)d_ws;
  ushort* Xh = (ushort*)(ws);                               // N*128 bf16, 25.6MB
  size_t off = (size_t)N * 256;
  int* csr   = (int*)(ws + off); off += (size_t)N * 256;    // 25.6MB
  int* stage = (int*)(ws + off); off += (size_t)NB * BSTRIDE * 4;  // 12.81MB
  int* cnt   = (int*)(ws + off); off += (size_t)N * 4;
  int* bcnt  = (int*)(ws + off); off += (size_t)NB * 4;     // contiguous w/ cnt
  float* dz  = (float*)(ws + off); off += (size_t)N * 4;
  float* wv  = (float*)(ws + off); off += 512;
  float* c0  = (float*)(ws + off);

  hipMemsetAsync(cnt, 0, (size_t)(N + NB) * 4, stream);     // cnt + bcnt
  hipLaunchKernelGGL(k_part1, dim3((E + CHUNK - 1) / CHUNK), dim3(256), 0, stream,
                     ei, bcnt, stage, cnt, E, N, NB);
  const int ngemm = (N + 63) / 64;
  hipLaunchKernelGGL(k_build, dim3(NB + ngemm + 1), dim3(256), 0, stream,
                     stage, bcnt, csr, cnt, x, W1, Xh, N, NB, ngemm,
                     W2, Wfc, b2, bfc, wv, c0);
  hipLaunchKernelGGL(k_agg1, dim3(((size_t)N * 64 + 255) / 256), dim3(256), 0, stream,
                     (const uint32*)Xh, csr, cnt, b1, wv, dz, N);
  hipLaunchKernelGGL(k_out,  dim3((N + 255) / 256), dim3(256), 0, stream,
                     dz, csr, cnt, c0, out, N);
}

// Round 13
// 150.996 us; speedup vs baseline: 9.4216x; 1.3844x over previous
//
#include <hip/hip_runtime.h>
#include <cstddef>

#define CAP 64
#define BK_SHIFT 8      // 256 nodes per bucket
#define GSLOT 1024      // stage slots per (group,bucket): mean 512, 22-sigma headroom
#define CHUNK 2048      // edges per workgroup in k_part1 (256 thr x 8)

typedef unsigned int uint32;
typedef unsigned short ushort;
typedef __attribute__((ext_vector_type(8))) short short8;
typedef __attribute__((ext_vector_type(4))) float f32x4;
typedef __attribute__((ext_vector_type(4))) int int4v;
typedef __attribute__((ext_vector_type(4))) float float4v;

__device__ __forceinline__ float bf_lo(uint32 v) {
  union { uint32 u; float f; } c; c.u = v << 16; return c.f;
}
__device__ __forceinline__ float bf_hi(uint32 v) {
  union { uint32 u; float f; } c; c.u = v & 0xffff0000u; return c.f;
}
__device__ __forceinline__ uint32 pack_bf2(float a, float b) {  // RNE
  union { float f; uint32 u; } x, y; x.f = a; y.f = b;
  uint32 ua = x.u + 0x7fffu + ((x.u >> 16) & 1u);
  uint32 ub = y.u + 0x7fffu + ((y.u >> 16) & 1u);
  return (ua >> 16) | (ub & 0xffff0000u);
}
__device__ __forceinline__ ushort bf16_1(float x) {  // RNE scalar
  union { float f; uint32 u; } c; c.f = x;
  return (ushort)((c.u + 0x7fffu + ((c.u >> 16) & 1u)) >> 16);
}

union ABu { uint32 u[4]; short8 v; };

// Phase 1: partition edges into 256-node buckets (packed (r<<8)|(c&255)).
// Stage is XCD-grouped: g = blockIdx&7 (round-robin block->XCD validated
// R10/R11), so each (g,bucket) slice is appended by ONE XCD only -> its
// tail 64B line stays in that XCD's L2 -> full-line write combining.
__global__ __launch_bounds__(256) void k_part1(const int* __restrict__ ei,
                                               int* __restrict__ bcnt,
                                               int* __restrict__ stage,
                                               int E, int N, int NB) {
  __shared__ int hist[512];
  __shared__ int gbase[512];
  const int tid = threadIdx.x;
  const int g   = blockIdx.x & 7;
  const int base = blockIdx.x * CHUNK;
  for (int b = tid; b < NB; b += 256) hist[b] = 0;
  __syncthreads();
  int rr[8], cc[8], lp[8];
  #pragma unroll
  for (int j = 0; j < 8; j++) {
    int e = base + tid + j * 256;
    int r = -1, c = -1;
    if (e < E) {
      r = __builtin_nontemporal_load(&ei[e]);
      c = __builtin_nontemporal_load(&ei[(size_t)E + e]);
    }
    bool ok = ((unsigned)r < (unsigned)N) && ((unsigned)c < (unsigned)N);
    rr[j] = ok ? r : -1;
    cc[j] = c;
    lp[j] = ok ? atomicAdd(&hist[c >> BK_SHIFT], 1) : 0;
  }
  __syncthreads();
  for (int b = tid; b < NB; b += 256) {
    int h = hist[b];
    gbase[b] = h ? atomicAdd(&bcnt[g * NB + b], h) : 0;
  }
  __syncthreads();
  #pragma unroll
  for (int j = 0; j < 8; j++) {
    if (rr[j] >= 0) {
      int b = cc[j] >> BK_SHIFT;
      int pos = gbase[b] + lp[j];
      if (pos < GSLOT)
        stage[((size_t)(g * NB + b) << 10) + pos] = (rr[j] << 8) | (cc[j] & 255);
    }
  }
}

// Phase 2: one workgroup per bucket; reads its 8 group slices (contiguous),
// csr writes confined to a 64KB window. Slots [deg, round8(deg)) padded with
// the node's own index. Writes cnt coalesced. Block NB = folded k_wc.
__global__ __launch_bounds__(256) void k_fill2(const int* __restrict__ stage,
                                               const int* __restrict__ bcnt,
                                               int* __restrict__ csr,
                                               int* __restrict__ cnt, int N, int NB,
                                               const float* __restrict__ W2,
                                               const float* __restrict__ Wfc,
                                               const float* __restrict__ b2,
                                               const float* __restrict__ bfc,
                                               float* __restrict__ wvo,
                                               float* __restrict__ c0) {
  const int b = blockIdx.x;
  const int tid = threadIdx.x;
  if (b == NB) {                      // folded k_wc
    if (tid < 128) {
      float s = 0.f;
      #pragma unroll 8
      for (int j = 0; j < 64; j++) s += W2[tid * 64 + j] * Wfc[j];
      wvo[tid] = s;
      if (tid == 0) {
        float cc = 0.f;
        for (int j = 0; j < 64; j++) cc += b2[j] * Wfc[j];
        c0[0] = cc + bfc[0];
      }
    }
    return;
  }
  __shared__ int lc[256];
  lc[tid] = 0;
  __syncthreads();
  const int node0 = b << BK_SHIFT;
  for (int g = 0; g < 8; g++) {
    int m = bcnt[g * NB + b]; if (m > GSLOT) m = GSLOT;
    const int* __restrict__ sb = stage + ((size_t)(g * NB + b) << 10);
    for (int e = tid; e < m; e += 256) {
      int v = __builtin_nontemporal_load(&sb[e]);
      int cl = v & 255;
      int pos = atomicAdd(&lc[cl], 1);
      if (pos < CAP) csr[(size_t)(node0 + cl) * CAP + pos] = v >> 8;
    }
  }
  __syncthreads();
  int node = node0 + tid;
  if (node < N) {
    int d = lc[tid]; if (d > CAP) d = CAP;
    cnt[node] = lc[tid];                 // true degree (rsqrt uses cnt+1)
    int d8 = (d + 7) & ~7; if (d8 > CAP) d8 = CAP;
    for (int p = d; p < d8; p++) csr[(size_t)node * CAP + p] = node;  // self-pad
  }
}

// Xh = bf16( dinv[row] * (X @ W1)[row,:] ) via bf16 MFMA 16x16x32.
__global__ __launch_bounds__(256) void k_gemm(const float* __restrict__ X,
                                              const float* __restrict__ W,
                                              const int* __restrict__ cnt,
                                              ushort* __restrict__ Xh, int M) {
  __shared__ ushort WtT[16384];   // 128 cols x 128 k, swizzled, 32 KB
  const int tid  = threadIdx.x;
  const int lane = tid & 63;
  const int wv   = tid >> 6;      // wave 0..3
  const int cl   = lane & 15;
  const int g    = lane >> 4;
  const int rb = blockIdx.x * 64 + wv * 16;

  int rowc = rb + cl; if (rowc >= M) rowc = M - 1;
  const float* xr = X + (size_t)rowc * 128;
  ABu af[4];
  #pragma unroll
  for (int kk = 0; kk < 4; kk++) {
    float4v p = __builtin_nontemporal_load((const float4v*)&xr[kk * 32 + g * 8]);
    float4v q = __builtin_nontemporal_load((const float4v*)&xr[kk * 32 + g * 8 + 4]);
    af[kk].u[0] = pack_bf2(p.x, p.y);
    af[kk].u[1] = pack_bf2(p.z, p.w);
    af[kk].u[2] = pack_bf2(q.x, q.y);
    af[kk].u[3] = pack_bf2(q.z, q.w);
  }

  float dvr[4];
  #pragma unroll
  for (int r = 0; r < 4; r++) {
    int rw = rb + g * 4 + r; if (rw >= M) rw = M - 1;
    dvr[r] = rsqrtf((float)(cnt[rw] + 1));
  }

  for (int idx = tid; idx < 8192; idx += 256) {
    int k = idx >> 6;
    int c = (idx & 63) * 2;
    float2 w2 = *(const float2*)&W[k * 128 + c];
    int gr = ((k >> 3) ^ ((c & 15) >> 1)) & 15;
    int base = (gr << 4) + (k & 7) * 2;
    *(ushort*)((char*)WtT + c * 256 + base)       = bf16_1(w2.x);
    *(ushort*)((char*)WtT + (c + 1) * 256 + base) = bf16_1(w2.y);
  }
  __syncthreads();

  #pragma unroll
  for (int ct = 0; ct < 8; ct++) {
    const char* wrow = (const char*)WtT + (ct * 16 + cl) * 256;
    f32x4 acc = {0.f, 0.f, 0.f, 0.f};
    #pragma unroll
    for (int kk = 0; kk < 4; kk++) {
      int grn = ((4 * kk + g) ^ (cl >> 1)) & 15;
      short8 bfrag = *(const short8*)(wrow + (grn << 4));
      acc = __builtin_amdgcn_mfma_f32_16x16x32_bf16(af[kk].v, bfrag, acc, 0, 0, 0);
    }
    #pragma unroll
    for (int r = 0; r < 4; r++) {
      int rw = rb + g * 4 + r;
      if (rw < M) Xh[(size_t)rw * 128 + ct * 16 + cl] = bf16_1(dvr[r] * acc[r]);
    }
  }
}

// One wave per node; tail-free unroll-8 gather over pre-scaled bf16 rows.
__global__ __launch_bounds__(256) void k_agg1(const uint32* __restrict__ Xh,
                                              const int* __restrict__ csr,
                                              const int* __restrict__ cnt,
                                              const float* __restrict__ b1,
                                              const float* __restrict__ wv,
                                              float* __restrict__ dz, int N) {
  int wid = (blockIdx.x * 256 + threadIdx.x) >> 6;
  int lane = threadIdx.x & 63;
  if (wid >= N) return;
  const int i = wid;
  int cv = cnt[i];
  int deg = cv; if (deg > CAP) deg = CAP;
  const int deg8 = (deg + 7) & ~7;
  const float di = rsqrtf((float)(cv + 1));
  int edge_reg = i;
  if (lane < deg8) edge_reg = __builtin_nontemporal_load(&csr[(size_t)i * CAP + lane]);

  uint32 vs = Xh[(size_t)i * 64 + lane];          // self-loop row
  float a0x = 0.f, a0y = 0.f, a1x = 0.f, a1y = 0.f;
  float a2x = 0.f, a2y = 0.f, a3x = 0.f, a3y = 0.f;
  float a4x = 0.f, a4y = 0.f, a5x = 0.f, a5y = 0.f;
  float a6x = 0.f, a6y = 0.f, a7x = 0.f, a7y = 0.f;

  for (int e = 0; e < deg8; e += 8) {
    int s0 = __builtin_amdgcn_readlane(edge_reg, e + 0);
    int s1 = __builtin_amdgcn_readlane(edge_reg, e + 1);
    int s2 = __builtin_amdgcn_readlane(edge_reg, e + 2);
    int s3 = __builtin_amdgcn_readlane(edge_reg, e + 3);
    int s4 = __builtin_amdgcn_readlane(edge_reg, e + 4);
    int s5 = __builtin_amdgcn_readlane(edge_reg, e + 5);
    int s6 = __builtin_amdgcn_readlane(edge_reg, e + 6);
    int s7 = __builtin_amdgcn_readlane(edge_reg, e + 7);
    uint32 v0 = Xh[(size_t)s0 * 64 + lane];
    uint32 v1 = Xh[(size_t)s1 * 64 + lane];
    uint32 v2 = Xh[(size_t)s2 * 64 + lane];
    uint32 v3 = Xh[(size_t)s3 * 64 + lane];
    uint32 v4 = Xh[(size_t)s4 * 64 + lane];
    uint32 v5 = Xh[(size_t)s5 * 64 + lane];
    uint32 v6 = Xh[(size_t)s6 * 64 + lane];
    uint32 v7 = Xh[(size_t)s7 * 64 + lane];
    a0x += bf_lo(v0); a0y += bf_hi(v0);
    a1x += bf_lo(v1); a1y += bf_hi(v1);
    a2x += bf_lo(v2); a2y += bf_hi(v2);
    a3x += bf_lo(v3); a3y += bf_hi(v3);
    a4x += bf_lo(v4); a4y += bf_hi(v4);
    a5x += bf_lo(v5); a5y += bf_hi(v5);
    a6x += bf_lo(v6); a6y += bf_hi(v6);
    a7x += bf_lo(v7); a7y += bf_hi(v7);
  }
  const float selfc = 1.0f - (float)(deg8 - deg);
  float sx = ((a0x + a1x) + (a2x + a3x)) + ((a4x + a5x) + (a6x + a7x));
  float sy = ((a0y + a1y) + (a2y + a3y)) + ((a4y + a5y) + (a6y + a7y));
  sx = fmaf(selfc, bf_lo(vs), sx);
  sy = fmaf(selfc, bf_hi(vs), sy);

  float2 bb = *(const float2*)&b1[lane * 2];
  float h0 = fmaxf(fmaf(di, sx, bb.x), 0.f);
  float h1 = fmaxf(fmaf(di, sy, bb.y), 0.f);
  float2 ww = *(const float2*)&wv[lane * 2];
  float part = fmaf(h0, ww.x, h1 * ww.y);
  #pragma unroll
  for (int m = 32; m > 0; m >>= 1) part += __shfl_xor(part, m, 64);
  if (lane == 0) dz[i] = di * part;
}

// out[i] = c0 + dinv[i] * (dz[i] + sum_in dz[src]); int4 csr loads over the
// self-padded deg8 range, padding corrected via (1 - npad) * dz[i].
__global__ __launch_bounds__(256) void k_out(const float* __restrict__ dz,
                                             const int* __restrict__ csr,
                                             const int* __restrict__ cnt,
                                             const float* __restrict__ c0,
                                             float* __restrict__ out, int N) {
  int i = blockIdx.x * 256 + threadIdx.x;
  if (i >= N) return;
  int cv = cnt[i];
  int deg = cv; if (deg > CAP) deg = CAP;
  const int deg8 = (deg + 7) & ~7;
  const int4v* __restrict__ edges = (const int4v*)(csr + (size_t)i * CAP);
  float s0 = (1.0f - (float)(deg8 - deg)) * dz[i];
  float s1 = 0.f, s2 = 0.f, s3 = 0.f;
  for (int e4 = 0; e4 < (deg8 >> 2); e4 += 2) {
    int4v q0 = __builtin_nontemporal_load(&edges[e4]);
    int4v q1 = __builtin_nontemporal_load(&edges[e4 + 1]);
    s0 += dz[q0.x]; s1 += dz[q0.y]; s2 += dz[q0.z]; s3 += dz[q0.w];
    s0 += dz[q1.x]; s1 += dz[q1.y]; s2 += dz[q1.z]; s3 += dz[q1.w];
  }
  out[i] = rsqrtf((float)(cv + 1)) * ((s0 + s1) + (s2 + s3)) + c0[0];
}

extern "C" void kernel_launch(void* const* d_in, const int* in_sizes, int n_in,
                              void* d_out, int out_size, void* d_ws, size_t ws_size,
                              hipStream_t stream) {
  const float* x   = (const float*)d_in[0];
  const int*   ei  = (const int*)d_in[1];   // int inputs arrive as int32
  // d_in[2] edge_weight: unused by reference
  const float* W1  = (const float*)d_in[3];
  const float* b1  = (const float*)d_in[4];
  const float* W2  = (const float*)d_in[5];
  const float* b2  = (const float*)d_in[6];
  const float* Wfc = (const float*)d_in[7];
  const float* bfc = (const float*)d_in[8];
  float* out = (float*)d_out;

  const int N = in_sizes[0] / 128;   // 100000
  const int E = in_sizes[1] / 2;     // 1600000
  const int NB = (N + 255) >> 8;     // 391 buckets

  // workspace layout (~65 MB)
  char* ws = (char*)d_ws;
  ushort* Xh = (ushort*)(ws);                               // N*128 bf16, 25.6MB
  size_t off = (size_t)N * 256;
  int* csr   = (int*)(ws + off); off += (size_t)N * 256;    // 25.6MB
  int* stage = (int*)(ws + off); off += (size_t)8 * NB * GSLOT * 4;  // 12.81MB
  int* cnt   = (int*)(ws + off); off += (size_t)N * 4;
  float* dz  = (float*)(ws + off); off += (size_t)N * 4;
  int* bcnt  = (int*)(ws + off); off += (size_t)8 * NB * 4;
  float* wv  = (float*)(ws + off); off += 512;
  float* c0  = (float*)(ws + off);

  hipMemsetAsync(bcnt, 0, (size_t)8 * NB * 4, stream);
  hipLaunchKernelGGL(k_part1, dim3((E + CHUNK - 1) / CHUNK), dim3(256), 0, stream,
                     ei, bcnt, stage, E, N, NB);
  hipLaunchKernelGGL(k_fill2, dim3(NB + 1), dim3(256), 0, stream,
                     stage, bcnt, csr, cnt, N, NB, W2, Wfc, b2, bfc, wv, c0);
  hipLaunchKernelGGL(k_gemm,  dim3((N + 63) / 64), dim3(256), 0, stream,
                     x, W1, cnt, Xh, N);
  hipLaunchKernelGGL(k_agg1, dim3(((size_t)N * 64 + 255) / 256), dim3(256), 0, stream,
                     (const uint32*)Xh, csr, cnt, b1, wv, dz, N);
  hipLaunchKernelGGL(k_out,  dim3((N + 255) / 256), dim3(256), 0, stream,
                     dz, csr, cnt, c0, out, N);
}